// Round 7
// baseline (351.414 us; speedup 1.0000x reference)
//
#include <hip/hip_runtime.h>
#include <hip/hip_bf16.h>
#include <hip/hip_cooperative_groups.h>

namespace cg = cooperative_groups;

#define B_    8
#define S_    512
#define DIN   1024
#define DOUT  1024
#define H_    8

using bf16x8 = __attribute__((ext_vector_type(8))) short;
using f32x4  = __attribute__((ext_vector_type(4))) float;

__device__ __forceinline__ ushort f2bf(float f) {
  __hip_bfloat16 h = __float2bfloat16(f);
  return *reinterpret_cast<ushort*>(&h);
}
__device__ __forceinline__ float bf2f(ushort u) {
  union { float f; unsigned int i; } v;
  v.i = ((unsigned int)u) << 16;
  return v.f;
}

__device__ __forceinline__ void gld16(const ushort* g, ushort* l) {
  __builtin_amdgcn_global_load_lds(
      (const __attribute__((address_space(1))) unsigned int*)g,
      (__attribute__((address_space(3))) unsigned int*)l, 16, 0, 0);
}

// One cooperative kernel, 512 blocks x 256 threads (2 blocks/CU co-resident).
// phase 0: x->bf16, W->WT, adj->bitmask | grid.sync | phase 1: proj GEMM (+s2/exp)
// | grid.sync | phase 2: (bit.*u)@V / rowsum.
__global__ __launch_bounds__(256) void k_mega(const float* __restrict__ x,
                                              ushort* __restrict__ xbf,
                                              const float* __restrict__ W,
                                              ushort* __restrict__ WT,
                                              const int* __restrict__ adj,
                                              unsigned long long* __restrict__ bm,
                                              const float* __restrict__ attw,
                                              const float* __restrict__ mask,
                                              ushort* __restrict__ xhT,
                                              ushort* __restrict__ ubf,
                                              float* __restrict__ out) {
  __shared__ __align__(16) char SMEM[27648];
  cg::grid_group grid = cg::this_grid();
  int blk = blockIdx.x;
  int t = threadIdx.x, lane = t & 63, wave = t >> 6;

  // ================= phase 0: prep =================
  {
    // ---- x fp32 -> bf16 (4 grid-stride passes, 8 elems/thread) ----
#pragma unroll
    for (int pass = 0; pass < 4; ++pass) {
      int i = (pass * 131072 + blk * 256 + t) * 8;
      const float4* p = reinterpret_cast<const float4*>(x + i);
      float4 a = p[0], b = p[1];
      ushort r[8];
      r[0] = f2bf(a.x); r[1] = f2bf(a.y); r[2] = f2bf(a.z); r[3] = f2bf(a.w);
      r[4] = f2bf(b.x); r[5] = f2bf(b.y); r[6] = f2bf(b.z); r[7] = f2bf(b.w);
      *reinterpret_cast<uint4*>(xbf + i) = *reinterpret_cast<uint4*>(r);
    }
    // ---- W[k][n] -> WT[n][k] bf16 (blocks 0..255, one 64x64 tile each) ----
    if (blk < 256) {
      float (*tile)[65] = reinterpret_cast<float(*)[65]>(SMEM);
      int r0 = (blk >> 4) * 64, c0 = (blk & 15) * 64;
      int lr = t >> 4, lc = (t & 15) * 4;
#pragma unroll
      for (int i = 0; i < 4; ++i) {
        int row = lr + i * 16;
        float4 v = *reinterpret_cast<const float4*>(&W[(size_t)(r0 + row) * DOUT + c0 + lc]);
        tile[row][lc] = v.x; tile[row][lc + 1] = v.y;
        tile[row][lc + 2] = v.z; tile[row][lc + 3] = v.w;
      }
      __syncthreads();
      int n = t >> 2, ks = (t & 3) * 16;
      ushort o[16];
#pragma unroll
      for (int i = 0; i < 16; ++i) o[i] = f2bf(tile[ks + i][n]);
      ushort* dst = &WT[(size_t)(c0 + n) * DIN + r0 + ks];
      reinterpret_cast<uint4*>(dst)[0] = reinterpret_cast<uint4*>(o)[0];
      reinterpret_cast<uint4*>(dst)[1] = reinterpret_cast<uint4*>(o)[1];
    }
    // ---- adj -> 64b bitmask (32768 words; 4 wave-groups x 16 iters) ----
    int grp = wave;
#pragma unroll
    for (int it = 0; it < 16; ++it) {
      int w = it * 2048 + blk * 4 + grp;
      int v = adj[(size_t)w * 64 + lane];
      unsigned long long m = __ballot(v != 0);
      if (lane == 0) bm[w] = m;
    }
  }
  __threadfence();
  grid.sync();

  // ================= phase 1: projection GEMM (64x128 tile, BK=64, swizzled) =================
  {
    ushort* As = reinterpret_cast<ushort*>(SMEM);           // [2][64][32] ushorts (8 KiB)
    ushort* Bs = reinterpret_cast<ushort*>(SMEM + 8192);    // [2][128][32] ushorts (16 KiB)
    ushort* Tr = reinterpret_cast<ushort*>(SMEM);           // 64*130 ushorts, aliases As/Bs post-loop
    float*  Pp = reinterpret_cast<float*>(SMEM + 24576);    // 256 floats

    int m0 = (blk >> 3) * 64;
    int h  = blk & 7;
    int r4 = t >> 2;
    int cswz = (((t & 3) ^ ((r4 >> 1) & 3)) << 3);          // pre-swizzled global source chunk

    const ushort* ga = &xbf[(size_t)(m0 + r4) * DIN + cswz];
    const ushort* gb = &WT[(size_t)(h * 128 + r4) * DIN + cswz];
    ushort* laA = As + t * 8;
    ushort* laB = Bs + t * 8;
    int rowa = lane & 15;
    int ksw = (((lane >> 4) ^ ((lane >> 1) & 3)) << 3);     // swizzled read k-offset
    int rbb = wave * 32 + (lane & 15);

    f32x4 acc[4][2] = {};

    for (int kt = 0; kt < DIN; kt += 64) {
      gld16(ga + kt,                 laA);
      gld16(ga + kt + 32,            laA + 2048);
      gld16(gb + kt,                 laB);
      gld16(gb + kt + 64 * DIN,      laB + 2048);
      gld16(gb + kt + 32,            laB + 4096);
      gld16(gb + kt + 32 + 64 * DIN, laB + 6144);
      asm volatile("s_waitcnt vmcnt(0)" ::: "memory");
      __syncthreads();
      bf16x8 a[4][2], bfr[2][2];
#pragma unroll
      for (int mi = 0; mi < 4; ++mi)
#pragma unroll
        for (int ks = 0; ks < 2; ++ks)
          a[mi][ks] = *reinterpret_cast<const bf16x8*>(&As[ks * 2048 + (rowa + mi * 16) * 32 + ksw]);
#pragma unroll
      for (int ni = 0; ni < 2; ++ni)
#pragma unroll
        for (int ks = 0; ks < 2; ++ks)
          bfr[ni][ks] = *reinterpret_cast<const bf16x8*>(&Bs[ks * 4096 + (rbb + ni * 16) * 32 + ksw]);
#pragma unroll
      for (int mi = 0; mi < 4; ++mi)
#pragma unroll
        for (int ni = 0; ni < 2; ++ni)
#pragma unroll
          for (int ks = 0; ks < 2; ++ks)
            acc[mi][ni] = __builtin_amdgcn_mfma_f32_16x16x32_bf16(a[mi][ks], bfr[ni][ks], acc[mi][ni], 0, 0, 0);
      __syncthreads();
    }

    // epilogue: acc -> Tr[s][d] (bf16); staging LDS is dead
    int colb = wave * 32 + (lane & 15);
    int rl = (lane >> 4) * 4;
#pragma unroll
    for (int mi = 0; mi < 4; ++mi)
#pragma unroll
      for (int ni = 0; ni < 2; ++ni) {
        int cc = colb + ni * 16;
#pragma unroll
        for (int j = 0; j < 4; ++j)
          Tr[(mi * 16 + rl + j) * 130 + cc] = f2bf(acc[mi][ni][j]);
      }
    __syncthreads();

    int b = m0 >> 9, s0 = m0 & 511;
    {
      int row = t >> 2, seg = (t & 3) * 32;
      float p = 0.f;
#pragma unroll 8
      for (int d = 0; d < 32; ++d)
        p += bf2f(Tr[row * 130 + seg + d]) * attw[128 + seg + d];
      Pp[row * 4 + (t & 3)] = p;
    }
    {
      int d = t >> 1, sseg = (t & 1) * 32;
      ushort* dst = &xhT[((size_t)(b * H_ + h) * 128 + d) * S_ + s0 + sseg];
#pragma unroll
      for (int g = 0; g < 4; ++g) {
        ushort o[8];
#pragma unroll
        for (int i = 0; i < 8; ++i) o[i] = Tr[(sseg + g * 8 + i) * 130 + d];
        reinterpret_cast<uint4*>(dst)[g] = *reinterpret_cast<uint4*>(o);
      }
    }
    __syncthreads();
    if (t < 64) {
      float s2 = Pp[t * 4] + Pp[t * 4 + 1] + Pp[t * 4 + 2] + Pp[t * 4 + 3];
      float mk = mask[b * S_ + s0 + t];
      float u = (mk > 0.f) ? __expf(s2) : 0.f;   // no max-subtract: s2 bounded ~[-1.5,1.5]
      ubf[(b * H_ + h) * S_ + s0 + t] = f2bf(u);
    }
  }
  __threadfence();
  grid.sync();

  // ================= phase 2: out = (bit .* u) @ V / rowsum =================
  {
    ushort* As = reinterpret_cast<ushort*>(SMEM);           // [2][64][32]
    ushort* Bs = reinterpret_cast<ushort*>(SMEM + 8192);    // [2][128][32]
    ushort* us = reinterpret_cast<ushort*>(SMEM + 24576);   // 512 ushorts
    float* Dred = reinterpret_cast<float*>(SMEM + 25600);   // 256 floats
    float* Dsum = reinterpret_cast<float*>(SMEM + 26624);   // 64 floats

    int b  = blk >> 6;
    int h  = (blk >> 3) & 7;
    int i0 = (blk & 7) * 64;

    if (t < 64)
      reinterpret_cast<uint4*>(us)[t] =
          reinterpret_cast<const uint4*>(&ubf[(b * H_ + h) * S_])[t];

    int r4 = t >> 2;
    int cswz = (((t & 3) ^ ((r4 >> 1) & 3)) << 3);
    const ushort* gv = &xhT[((size_t)(b * H_ + h) * 128 + r4) * S_ + cswz];
    ushort* laB = Bs + t * 8;

    int arow = t >> 2, cseg = (t & 3) * 16;
    const unsigned long long* bmrow = &bm[(size_t)(b * S_ + i0 + arow) * 8];
    int s_w = (arow >> 1) & 3;
    int cb = (cseg & 31) >> 3;
    ushort* awbase = As + ((cseg >= 32) ? 2048 : 0) + arow * 32;
    ushort* aw0 = awbase + (((cb) ^ s_w) << 3);
    ushort* aw1 = awbase + (((cb + 1) ^ s_w) << 3);

    float dacc = 0.f;
    f32x4 acc[4][2] = {};
    int rowa = lane & 15;
    int ksw = (((lane >> 4) ^ ((lane >> 1) & 3)) << 3);
    int rbb = wave * 32 + (lane & 15);

    __syncthreads();   // us visible

    for (int kt = 0; kt < S_; kt += 64) {
      gld16(gv + kt,                laB);
      gld16(gv + kt + 64 * S_,      laB + 2048);
      gld16(gv + kt + 32,           laB + 4096);
      gld16(gv + kt + 32 + 64 * S_, laB + 6144);
      unsigned long long w = bmrow[kt >> 6];
      unsigned int bits = (unsigned int)(w >> cseg) & 0xffffu;
      ushort uu[16];
      *reinterpret_cast<uint4*>(uu)     = *reinterpret_cast<const uint4*>(&us[kt + cseg]);
      *reinterpret_cast<uint4*>(uu + 8) = *reinterpret_cast<const uint4*>(&us[kt + cseg + 8]);
      ushort av[16];
#pragma unroll
      for (int q = 0; q < 16; ++q) {
        bool nz = (bits >> q) & 1;
        av[q] = nz ? uu[q] : (ushort)0;
        dacc += nz ? bf2f(uu[q]) : 0.f;
      }
      *reinterpret_cast<uint4*>(aw0) = reinterpret_cast<uint4*>(av)[0];
      *reinterpret_cast<uint4*>(aw1) = reinterpret_cast<uint4*>(av)[1];
      asm volatile("s_waitcnt vmcnt(0)" ::: "memory");
      __syncthreads();
      bf16x8 a[4][2], bfr[2][2];
#pragma unroll
      for (int mi = 0; mi < 4; ++mi)
#pragma unroll
        for (int ks = 0; ks < 2; ++ks)
          a[mi][ks] = *reinterpret_cast<const bf16x8*>(&As[ks * 2048 + (rowa + mi * 16) * 32 + ksw]);
#pragma unroll
      for (int ni = 0; ni < 2; ++ni)
#pragma unroll
        for (int ks = 0; ks < 2; ++ks)
          bfr[ni][ks] = *reinterpret_cast<const bf16x8*>(&Bs[ks * 4096 + (rbb + ni * 16) * 32 + ksw]);
#pragma unroll
      for (int mi = 0; mi < 4; ++mi)
#pragma unroll
        for (int ni = 0; ni < 2; ++ni)
#pragma unroll
          for (int ks = 0; ks < 2; ++ks)
            acc[mi][ni] = __builtin_amdgcn_mfma_f32_16x16x32_bf16(a[mi][ks], bfr[ni][ks], acc[mi][ni], 0, 0, 0);
      __syncthreads();
    }

    Dred[arow * 4 + (t & 3)] = dacc;
    __syncthreads();
    if (t < 64)
      Dsum[t] = Dred[t * 4] + Dred[t * 4 + 1] + Dred[t * 4 + 2] + Dred[t * 4 + 3];
    __syncthreads();

    int colb = wave * 32 + (lane & 15);
    int rl = (lane >> 4) * 4;
#pragma unroll
    for (int mi = 0; mi < 4; ++mi)
#pragma unroll
      for (int ni = 0; ni < 2; ++ni) {
        int cc = colb + ni * 16;
#pragma unroll
        for (int j = 0; j < 4; ++j) {
          int rr = mi * 16 + rl + j;
          float Di = fmaxf(Dsum[rr], 1e-30f);
          out[((size_t)(b * S_ + i0 + rr)) * DOUT + h * 128 + cc] = acc[mi][ni][j] / Di;
        }
      }
  }
}

// ---------------- launch ----------------
extern "C" void kernel_launch(void* const* d_in, const int* in_sizes, int n_in,
                              void* d_out, int out_size, void* d_ws, size_t ws_size,
                              hipStream_t stream) {
  const float* x    = (const float*)d_in[0];
  const float* mask = (const float*)d_in[1];
  const int*   adj  = (const int*)d_in[2];
  const float* W    = (const float*)d_in[3];
  const float* attw = (const float*)d_in[4];
  float* out = (float*)d_out;

  char* ws = (char*)d_ws;
  ushort* xbf = (ushort*)ws;                               // 8 MiB
  ushort* WT  = (ushort*)(ws + 8388608);                   // 2 MiB
  ushort* xhT = (ushort*)(ws + 10485760);                  // 8 MiB
  ushort* ubf = (ushort*)(ws + 18874368);                  // 64 KiB
  unsigned long long* bm = (unsigned long long*)(ws + 18939904);  // 256 KiB

  void* args[] = {(void*)&x, (void*)&xbf, (void*)&W, (void*)&WT, (void*)&adj,
                  (void*)&bm, (void*)&attw, (void*)&mask, (void*)&xhT,
                  (void*)&ubf, (void*)&out};
  hipLaunchCooperativeKernel((const void*)k_mega, dim3(512), dim3(256),
                             args, 0, stream);
}

// Round 8
// 121.507 us; speedup vs baseline: 2.8921x; 2.8921x over previous
//
#include <hip/hip_runtime.h>
#include <hip/hip_bf16.h>

#define B_    8
#define S_    512
#define DIN   1024
#define DOUT  1024
#define H_    8

using bf16x8 = __attribute__((ext_vector_type(8))) short;
using f32x4  = __attribute__((ext_vector_type(4))) float;

__device__ __forceinline__ ushort f2bf(float f) {
  __hip_bfloat16 h = __float2bfloat16(f);
  return *reinterpret_cast<ushort*>(&h);
}
__device__ __forceinline__ float bf2f(ushort u) {
  union { float f; unsigned int i; } v;
  v.i = ((unsigned int)u) << 16;
  return v.f;
}

__device__ __forceinline__ void gld16(const ushort* g, ushort* l) {
  __builtin_amdgcn_global_load_lds(
      (const __attribute__((address_space(1))) unsigned int*)g,
      (__attribute__((address_space(3))) unsigned int*)l, 16, 0, 0);
}

// ---------------- kernel 1: prep = W->WT bf16 | adj->bitmask ----------------
// blocks [0,256): W transpose; [256,8448): bitpack
__global__ __launch_bounds__(256) void k_prep(const float* __restrict__ W,
                                              ushort* __restrict__ WT,
                                              const int* __restrict__ adj,
                                              unsigned long long* __restrict__ bm) {
  __shared__ float tile[64][65];
  int blk = blockIdx.x;
  int t = threadIdx.x;
  if (blk < 256) {
    int r0 = (blk >> 4) * 64, c0 = (blk & 15) * 64;
    int lr = t >> 4, lc = (t & 15) * 4;
#pragma unroll
    for (int i = 0; i < 4; ++i) {
      int row = lr + i * 16;
      float4 v = *reinterpret_cast<const float4*>(&W[(size_t)(r0 + row) * DOUT + c0 + lc]);
      tile[row][lc] = v.x; tile[row][lc + 1] = v.y;
      tile[row][lc + 2] = v.z; tile[row][lc + 3] = v.w;
    }
    __syncthreads();
    int n = t >> 2, ks = (t & 3) * 16;
    ushort o[16];
#pragma unroll
    for (int i = 0; i < 16; ++i) o[i] = f2bf(tile[ks + i][n]);
    ushort* dst = &WT[(size_t)(c0 + n) * DIN + r0 + ks];
    reinterpret_cast<uint4*>(dst)[0] = reinterpret_cast<uint4*>(o)[0];
    reinterpret_cast<uint4*>(dst)[1] = reinterpret_cast<uint4*>(o)[1];
  } else {
    int w = (blk - 256) * 4 + (t >> 6);        // 64-element word index
    int lane = t & 63;
    int v = adj[(size_t)w * 64 + lane];
    unsigned long long m = __ballot(v != 0);
    if (lane == 0) bm[w] = m;
  }
}

// ---------------- kernel 2: projection GEMM (64x128 tile, BK=64, swizzled) ----------------
// A-operand staged from x (fp32) with in-register bf16 conversion (xbf eliminated).
// B-operand staged from WT via global_load_lds. Writes xhT[b,h,d,s] + ubf.
__global__ __launch_bounds__(256) void k_proj(const float* __restrict__ x,
                                              const ushort* __restrict__ WT,
                                              const float* __restrict__ attw,
                                              const float* __restrict__ mask,
                                              ushort* __restrict__ xhT,
                                              ushort* __restrict__ ubf) {
  __shared__ __align__(16) ushort As[2 * 64 * 32];    // [half][row64][k32]
  __shared__ __align__(16) ushort Bs[2 * 128 * 32];   // [half][row128][k32]
  __shared__ __align__(16) ushort Tr[64 * 130];
  __shared__ float Pp[64 * 4];
  int m0 = blockIdx.x * 64;   // linear = h*64 + m-idx -> same-m blocks share an XCD
  int h  = blockIdx.y;
  int t = threadIdx.x, lane = t & 63, wave = t >> 6;  // 4 waves: 1M x 4N
  int r4 = t >> 2;
  int cswz = (((t & 3) ^ ((r4 >> 1) & 3)) << 3);      // pre-swizzled source chunk

  const float*  gx = &x[(size_t)(m0 + r4) * DIN + cswz];
  const ushort* gb = &WT[(size_t)(h * 128 + r4) * DIN + cswz];
  ushort* laB = Bs + t * 8;
  int rowa = lane & 15;
  int ksw = (((lane >> 4) ^ ((lane >> 1) & 3)) << 3); // swizzled read k-offset
  int rbb = wave * 32 + (lane & 15);

  f32x4 acc[4][2] = {};

  for (int kt = 0; kt < DIN; kt += 64) {
    // A: reg-staged fp32 -> bf16 (same swizzled mapping as the old gld16 path)
    float4 a0 = *reinterpret_cast<const float4*>(gx + kt);
    float4 a1 = *reinterpret_cast<const float4*>(gx + kt + 4);
    float4 b0 = *reinterpret_cast<const float4*>(gx + kt + 32);
    float4 b1 = *reinterpret_cast<const float4*>(gx + kt + 36);
    // B: direct-to-LDS
    gld16(gb + kt,                 laB);
    gld16(gb + kt + 64 * DIN,      laB + 2048);
    gld16(gb + kt + 32,            laB + 4096);
    gld16(gb + kt + 32 + 64 * DIN, laB + 6144);
    ushort r0[8], r1[8];
    r0[0] = f2bf(a0.x); r0[1] = f2bf(a0.y); r0[2] = f2bf(a0.z); r0[3] = f2bf(a0.w);
    r0[4] = f2bf(a1.x); r0[5] = f2bf(a1.y); r0[6] = f2bf(a1.z); r0[7] = f2bf(a1.w);
    r1[0] = f2bf(b0.x); r1[1] = f2bf(b0.y); r1[2] = f2bf(b0.z); r1[3] = f2bf(b0.w);
    r1[4] = f2bf(b1.x); r1[5] = f2bf(b1.y); r1[6] = f2bf(b1.z); r1[7] = f2bf(b1.w);
    *reinterpret_cast<uint4*>(&As[t * 8])        = *reinterpret_cast<uint4*>(r0);
    *reinterpret_cast<uint4*>(&As[t * 8 + 2048]) = *reinterpret_cast<uint4*>(r1);
    asm volatile("s_waitcnt vmcnt(0)" ::: "memory");
    __syncthreads();
    bf16x8 a[4][2], bfr[2][2];
#pragma unroll
    for (int mi = 0; mi < 4; ++mi)
#pragma unroll
      for (int ks = 0; ks < 2; ++ks)
        a[mi][ks] = *reinterpret_cast<const bf16x8*>(&As[ks * 2048 + (rowa + mi * 16) * 32 + ksw]);
#pragma unroll
    for (int ni = 0; ni < 2; ++ni)
#pragma unroll
      for (int ks = 0; ks < 2; ++ks)
        bfr[ni][ks] = *reinterpret_cast<const bf16x8*>(&Bs[ks * 4096 + (rbb + ni * 16) * 32 + ksw]);
#pragma unroll
    for (int mi = 0; mi < 4; ++mi)
#pragma unroll
      for (int ni = 0; ni < 2; ++ni)
#pragma unroll
        for (int ks = 0; ks < 2; ++ks)
          acc[mi][ni] = __builtin_amdgcn_mfma_f32_16x16x32_bf16(a[mi][ks], bfr[ni][ks], acc[mi][ni], 0, 0, 0);
    __syncthreads();
  }

  // epilogue: acc -> Tr[s][d] (bf16)
  int colb = wave * 32 + (lane & 15);
  int rl = (lane >> 4) * 4;
#pragma unroll
  for (int mi = 0; mi < 4; ++mi)
#pragma unroll
    for (int ni = 0; ni < 2; ++ni) {
      int cc = colb + ni * 16;
#pragma unroll
      for (int j = 0; j < 4; ++j)
        Tr[(mi * 16 + rl + j) * 130 + cc] = f2bf(acc[mi][ni][j]);
    }
  __syncthreads();

  int b = m0 >> 9, s0 = m0 & 511;
  // s2 partials (4 threads per row, 32 d each)
  {
    int row = t >> 2, seg = (t & 3) * 32;
    float p = 0.f;
#pragma unroll 8
    for (int d = 0; d < 32; ++d)
      p += bf2f(Tr[row * 130 + seg + d]) * attw[128 + seg + d];
    Pp[row * 4 + (t & 3)] = p;
  }
  // xhT store: thread t -> d = t>>1, s-seg of 32
  {
    int d = t >> 1, sseg = (t & 1) * 32;
    ushort* dst = &xhT[((size_t)(b * H_ + h) * 128 + d) * S_ + s0 + sseg];
#pragma unroll
    for (int g = 0; g < 4; ++g) {
      ushort o[8];
#pragma unroll
      for (int i = 0; i < 8; ++i) o[i] = Tr[(sseg + g * 8 + i) * 130 + d];
      reinterpret_cast<uint4*>(dst)[g] = *reinterpret_cast<uint4*>(o);
    }
  }
  __syncthreads();
  if (t < 64) {
    float s2 = Pp[t * 4] + Pp[t * 4 + 1] + Pp[t * 4 + 2] + Pp[t * 4 + 3];
    float mk = mask[b * S_ + s0 + t];
    float u = (mk > 0.f) ? __expf(s2) : 0.f;   // no max-subtract: s2 bounded ~[-1.5,1.5]
    ubf[(b * H_ + h) * S_ + s0 + t] = f2bf(u);
  }
}

// ---------------- kernel 3: out = (bit .* u) @ V / rowsum  (64x128 tile, BK=64, swizzled) ----------------
// grid (h, b, i0): same-(b,h) blocks at linear stride 64 -> same XCD -> V-strip L2 reuse.
__global__ __launch_bounds__(256) void k_attn(const unsigned long long* __restrict__ bm,
                                              const ushort* __restrict__ xhT,
                                              const ushort* __restrict__ ubf,
                                              float* __restrict__ out) {
  __shared__ __align__(16) ushort As[2 * 64 * 32];
  __shared__ __align__(16) ushort Bs[2 * 128 * 32];
  __shared__ __align__(16) ushort us[512];
  __shared__ float Dred[64 * 4];
  __shared__ float Dsum[64];
  int h  = blockIdx.x;
  int b  = blockIdx.y;
  int i0 = blockIdx.z * 64;
  int t = threadIdx.x, lane = t & 63, wave = t >> 6;

  if (t < 64)
    reinterpret_cast<uint4*>(us)[t] =
        reinterpret_cast<const uint4*>(&ubf[(b * H_ + h) * S_])[t];

  int r4 = t >> 2;
  int cswz = (((t & 3) ^ ((r4 >> 1) & 3)) << 3);
  const ushort* gv = &xhT[((size_t)(b * H_ + h) * 128 + r4) * S_ + cswz];
  ushort* laB = Bs + t * 8;

  int arow = t >> 2, cseg = (t & 3) * 16;
  const unsigned long long* bmrow = &bm[(size_t)(b * S_ + i0 + arow) * 8];
  int s_w = (arow >> 1) & 3;                    // write-side swizzle for this row
  int cb = (cseg & 31) >> 3;                    // chunk base within half: 0 or 2
  ushort* awbase = As + ((cseg >= 32) ? 2048 : 0) + arow * 32;
  ushort* aw0 = awbase + (((cb) ^ s_w) << 3);
  ushort* aw1 = awbase + (((cb + 1) ^ s_w) << 3);

  float dacc = 0.f;
  f32x4 acc[4][2] = {};
  int rowa = lane & 15;
  int ksw = (((lane >> 4) ^ ((lane >> 1) & 3)) << 3);
  int rbb = wave * 32 + (lane & 15);

  __syncthreads();   // us ready

  for (int kt = 0; kt < S_; kt += 64) {
    gld16(gv + kt,                laB);
    gld16(gv + kt + 64 * S_,      laB + 2048);
    gld16(gv + kt + 32,           laB + 4096);
    gld16(gv + kt + 32 + 64 * S_, laB + 6144);
    unsigned long long w = bmrow[kt >> 6];
    unsigned int bits = (unsigned int)(w >> cseg) & 0xffffu;
    ushort uu[16];
    *reinterpret_cast<uint4*>(uu)     = *reinterpret_cast<const uint4*>(&us[kt + cseg]);
    *reinterpret_cast<uint4*>(uu + 8) = *reinterpret_cast<const uint4*>(&us[kt + cseg + 8]);
    ushort av[16];
#pragma unroll
    for (int q = 0; q < 16; ++q) {
      bool nz = (bits >> q) & 1;
      av[q] = nz ? uu[q] : (ushort)0;
      dacc += nz ? bf2f(uu[q]) : 0.f;
    }
    *reinterpret_cast<uint4*>(aw0) = reinterpret_cast<uint4*>(av)[0];
    *reinterpret_cast<uint4*>(aw1) = reinterpret_cast<uint4*>(av)[1];
    asm volatile("s_waitcnt vmcnt(0)" ::: "memory");
    __syncthreads();
    bf16x8 a[4][2], bfr[2][2];
#pragma unroll
    for (int mi = 0; mi < 4; ++mi)
#pragma unroll
      for (int ks = 0; ks < 2; ++ks)
        a[mi][ks] = *reinterpret_cast<const bf16x8*>(&As[ks * 2048 + (rowa + mi * 16) * 32 + ksw]);
#pragma unroll
    for (int ni = 0; ni < 2; ++ni)
#pragma unroll
      for (int ks = 0; ks < 2; ++ks)
        bfr[ni][ks] = *reinterpret_cast<const bf16x8*>(&Bs[ks * 4096 + (rbb + ni * 16) * 32 + ksw]);
#pragma unroll
    for (int mi = 0; mi < 4; ++mi)
#pragma unroll
      for (int ni = 0; ni < 2; ++ni)
#pragma unroll
        for (int ks = 0; ks < 2; ++ks)
          acc[mi][ni] = __builtin_amdgcn_mfma_f32_16x16x32_bf16(a[mi][ks], bfr[ni][ks], acc[mi][ni], 0, 0, 0);
    __syncthreads();
  }

  Dred[arow * 4 + (t & 3)] = dacc;
  __syncthreads();
  if (t < 64)
    Dsum[t] = Dred[t * 4] + Dred[t * 4 + 1] + Dred[t * 4 + 2] + Dred[t * 4 + 3];
  __syncthreads();

  int colb = wave * 32 + (lane & 15);
  int rl = (lane >> 4) * 4;
#pragma unroll
  for (int mi = 0; mi < 4; ++mi)
#pragma unroll
    for (int ni = 0; ni < 2; ++ni) {
      int cc = colb + ni * 16;
#pragma unroll
      for (int j = 0; j < 4; ++j) {
        int rr = mi * 16 + rl + j;
        float Di = fmaxf(Dsum[rr], 1e-30f);
        out[((size_t)(b * S_ + i0 + rr)) * DOUT + h * 128 + cc] = acc[mi][ni][j] / Di;
      }
    }
}

// ---------------- launch ----------------
extern "C" void kernel_launch(void* const* d_in, const int* in_sizes, int n_in,
                              void* d_out, int out_size, void* d_ws, size_t ws_size,
                              hipStream_t stream) {
  const float* x    = (const float*)d_in[0];
  const float* mask = (const float*)d_in[1];
  const int*   adj  = (const int*)d_in[2];
  const float* W    = (const float*)d_in[3];
  const float* attw = (const float*)d_in[4];
  float* out = (float*)d_out;

  char* ws = (char*)d_ws;
  ushort* WT  = (ushort*)ws;                               // 2 MiB (1024x1024 bf16, transposed)
  ushort* xhT = (ushort*)(ws + 2097152);                   // 8 MiB (B,H,128,512 bf16)
  ushort* ubf = (ushort*)(ws + 10485760);                  // 64 KiB
  unsigned long long* bm = (unsigned long long*)(ws + 10551296);  // 256 KiB

  k_prep<<<dim3(8448), dim3(256), 0, stream>>>(W, WT, adj, bm);
  k_proj<<<dim3(64, 8), dim3(256), 0, stream>>>(x, WT, attw, mask, xhT, ubf);
  k_attn<<<dim3(8, 8, 8), dim3(256), 0, stream>>>(bm, xhT, ubf, out);
}

// Round 9
// 119.580 us; speedup vs baseline: 2.9387x; 1.0161x over previous
//
#include <hip/hip_runtime.h>
#include <hip/hip_bf16.h>

#define B_    8
#define S_    512
#define DIN   1024
#define DOUT  1024
#define H_    8

using bf16x8 = __attribute__((ext_vector_type(8))) short;
using f32x4  = __attribute__((ext_vector_type(4))) float;

__device__ __forceinline__ ushort f2bf(float f) {
  __hip_bfloat16 h = __float2bfloat16(f);
  return *reinterpret_cast<ushort*>(&h);
}
__device__ __forceinline__ float bf2f(ushort u) {
  union { float f; unsigned int i; } v;
  v.i = ((unsigned int)u) << 16;
  return v.f;
}

__device__ __forceinline__ void gld16(const ushort* g, ushort* l) {
  __builtin_amdgcn_global_load_lds(
      (const __attribute__((address_space(1))) unsigned int*)g,
      (__attribute__((address_space(3))) unsigned int*)l, 16, 0, 0);
}

// ---------------- kernel 1: W[k][n] -> WT[n][k] bf16 (256 blocks) ----------------
__global__ __launch_bounds__(256) void k_prep(const float* __restrict__ W,
                                              ushort* __restrict__ WT) {
  __shared__ float tile[64][65];
  int blk = blockIdx.x;
  int t = threadIdx.x;
  int r0 = (blk >> 4) * 64, c0 = (blk & 15) * 64;
  int lr = t >> 4, lc = (t & 15) * 4;
#pragma unroll
  for (int i = 0; i < 4; ++i) {
    int row = lr + i * 16;
    float4 v = *reinterpret_cast<const float4*>(&W[(size_t)(r0 + row) * DOUT + c0 + lc]);
    tile[row][lc] = v.x; tile[row][lc + 1] = v.y;
    tile[row][lc + 2] = v.z; tile[row][lc + 3] = v.w;
  }
  __syncthreads();
  int n = t >> 2, ks = (t & 3) * 16;
  ushort o[16];
#pragma unroll
  for (int i = 0; i < 16; ++i) o[i] = f2bf(tile[ks + i][n]);
  ushort* dst = &WT[(size_t)(c0 + n) * DIN + r0 + ks];
  reinterpret_cast<uint4*>(dst)[0] = reinterpret_cast<uint4*>(o)[0];
  reinterpret_cast<uint4*>(dst)[1] = reinterpret_cast<uint4*>(o)[1];
}

// ---------------- kernel 2: projection GEMM (64x128 tile, BK=64, swizzled) ----------------
// A staged from x (fp32) with in-register bf16 conversion; B via global_load_lds from WT.
// Writes xhT[b,h,d,s] + ubf.
__global__ __launch_bounds__(256) void k_proj(const float* __restrict__ x,
                                              const ushort* __restrict__ WT,
                                              const float* __restrict__ attw,
                                              const float* __restrict__ mask,
                                              ushort* __restrict__ xhT,
                                              ushort* __restrict__ ubf) {
  __shared__ __align__(16) ushort As[2 * 64 * 32];    // [half][row64][k32]
  __shared__ __align__(16) ushort Bs[2 * 128 * 32];   // [half][row128][k32]
  __shared__ __align__(16) ushort Tr[64 * 130];
  __shared__ float Pp[64 * 4];
  int m0 = blockIdx.x * 64;
  int h  = blockIdx.y;
  int t = threadIdx.x, lane = t & 63, wave = t >> 6;  // 4 waves: 1M x 4N
  int r4 = t >> 2;
  int cswz = (((t & 3) ^ ((r4 >> 1) & 3)) << 3);      // pre-swizzled source chunk

  const float*  gx = &x[(size_t)(m0 + r4) * DIN + cswz];
  const ushort* gb = &WT[(size_t)(h * 128 + r4) * DIN + cswz];
  ushort* laB = Bs + t * 8;
  int rowa = lane & 15;
  int ksw = (((lane >> 4) ^ ((lane >> 1) & 3)) << 3); // swizzled read k-offset
  int rbb = wave * 32 + (lane & 15);

  f32x4 acc[4][2] = {};

  for (int kt = 0; kt < DIN; kt += 64) {
    float4 a0 = *reinterpret_cast<const float4*>(gx + kt);
    float4 a1 = *reinterpret_cast<const float4*>(gx + kt + 4);
    float4 b0 = *reinterpret_cast<const float4*>(gx + kt + 32);
    float4 b1 = *reinterpret_cast<const float4*>(gx + kt + 36);
    gld16(gb + kt,                 laB);
    gld16(gb + kt + 64 * DIN,      laB + 2048);
    gld16(gb + kt + 32,            laB + 4096);
    gld16(gb + kt + 32 + 64 * DIN, laB + 6144);
    ushort r0[8], r1[8];
    r0[0] = f2bf(a0.x); r0[1] = f2bf(a0.y); r0[2] = f2bf(a0.z); r0[3] = f2bf(a0.w);
    r0[4] = f2bf(a1.x); r0[5] = f2bf(a1.y); r0[6] = f2bf(a1.z); r0[7] = f2bf(a1.w);
    r1[0] = f2bf(b0.x); r1[1] = f2bf(b0.y); r1[2] = f2bf(b0.z); r1[3] = f2bf(b0.w);
    r1[4] = f2bf(b1.x); r1[5] = f2bf(b1.y); r1[6] = f2bf(b1.z); r1[7] = f2bf(b1.w);
    *reinterpret_cast<uint4*>(&As[t * 8])        = *reinterpret_cast<uint4*>(r0);
    *reinterpret_cast<uint4*>(&As[t * 8 + 2048]) = *reinterpret_cast<uint4*>(r1);
    asm volatile("s_waitcnt vmcnt(0)" ::: "memory");
    __syncthreads();
    bf16x8 a[4][2], bfr[2][2];
#pragma unroll
    for (int mi = 0; mi < 4; ++mi)
#pragma unroll
      for (int ks = 0; ks < 2; ++ks)
        a[mi][ks] = *reinterpret_cast<const bf16x8*>(&As[ks * 2048 + (rowa + mi * 16) * 32 + ksw]);
#pragma unroll
    for (int ni = 0; ni < 2; ++ni)
#pragma unroll
      for (int ks = 0; ks < 2; ++ks)
        bfr[ni][ks] = *reinterpret_cast<const bf16x8*>(&Bs[ks * 4096 + (rbb + ni * 16) * 32 + ksw]);
#pragma unroll
    for (int mi = 0; mi < 4; ++mi)
#pragma unroll
      for (int ni = 0; ni < 2; ++ni)
#pragma unroll
        for (int ks = 0; ks < 2; ++ks)
          acc[mi][ni] = __builtin_amdgcn_mfma_f32_16x16x32_bf16(a[mi][ks], bfr[ni][ks], acc[mi][ni], 0, 0, 0);
    __syncthreads();
  }

  // epilogue: acc -> Tr[s][d] (bf16)
  int colb = wave * 32 + (lane & 15);
  int rl = (lane >> 4) * 4;
#pragma unroll
  for (int mi = 0; mi < 4; ++mi)
#pragma unroll
    for (int ni = 0; ni < 2; ++ni) {
      int cc = colb + ni * 16;
#pragma unroll
      for (int j = 0; j < 4; ++j)
        Tr[(mi * 16 + rl + j) * 130 + cc] = f2bf(acc[mi][ni][j]);
    }
  __syncthreads();

  int b = m0 >> 9, s0 = m0 & 511;
  {
    int row = t >> 2, seg = (t & 3) * 32;
    float p = 0.f;
#pragma unroll 8
    for (int d = 0; d < 32; ++d)
      p += bf2f(Tr[row * 130 + seg + d]) * attw[128 + seg + d];
    Pp[row * 4 + (t & 3)] = p;
  }
  {
    int d = t >> 1, sseg = (t & 1) * 32;
    ushort* dst = &xhT[((size_t)(b * H_ + h) * 128 + d) * S_ + s0 + sseg];
#pragma unroll
    for (int g = 0; g < 4; ++g) {
      ushort o[8];
#pragma unroll
      for (int i = 0; i < 8; ++i) o[i] = Tr[(sseg + g * 8 + i) * 130 + d];
      reinterpret_cast<uint4*>(dst)[g] = *reinterpret_cast<uint4*>(o);
    }
  }
  __syncthreads();
  if (t < 64) {
    float s2 = Pp[t * 4] + Pp[t * 4 + 1] + Pp[t * 4 + 2] + Pp[t * 4 + 3];
    float mk = mask[b * S_ + s0 + t];
    float u = (mk > 0.f) ? __expf(s2) : 0.f;   // no max-subtract: s2 bounded ~[-1.5,1.5]
    ubf[(b * H_ + h) * S_ + s0 + t] = f2bf(u);
  }
}

// ---------------- kernel 3: out = (adj .* u) @ V / rowsum  (adj read direct, swizzled LDS) ----------------
// grid (h, b, i0): consecutive blocks share the adj slice (L2).
__global__ __launch_bounds__(256) void k_attn(const int* __restrict__ adj,
                                              const ushort* __restrict__ xhT,
                                              const ushort* __restrict__ ubf,
                                              float* __restrict__ out) {
  __shared__ __align__(16) ushort As[2 * 64 * 32];
  __shared__ __align__(16) ushort Bs[2 * 128 * 32];
  __shared__ __align__(16) ushort us[512];
  __shared__ float Dred[64 * 4];
  __shared__ float Dsum[64];
  int h  = blockIdx.x;
  int b  = blockIdx.y;
  int i0 = blockIdx.z * 64;
  int t = threadIdx.x, lane = t & 63, wave = t >> 6;

  if (t < 64)
    reinterpret_cast<uint4*>(us)[t] =
        reinterpret_cast<const uint4*>(&ubf[(b * H_ + h) * S_])[t];

  int r4 = t >> 2;
  int cswz = (((t & 3) ^ ((r4 >> 1) & 3)) << 3);
  const ushort* gv = &xhT[((size_t)(b * H_ + h) * 128 + r4) * S_ + cswz];
  ushort* laB = Bs + t * 8;

  int arow = t >> 2, cseg = (t & 3) * 16;
  const int* arowp = &adj[((size_t)(b * S_ + i0 + arow)) * S_ + cseg];
  int s_w = (arow >> 1) & 3;                    // write-side swizzle for this row
  int cb = (cseg & 31) >> 3;                    // chunk base within half: 0 or 2
  ushort* awbase = As + ((cseg >= 32) ? 2048 : 0) + arow * 32;
  ushort* aw0 = awbase + (((cb) ^ s_w) << 3);
  ushort* aw1 = awbase + (((cb + 1) ^ s_w) << 3);

  float dacc = 0.f;
  f32x4 acc[4][2] = {};
  int rowa = lane & 15;
  int ksw = (((lane >> 4) ^ ((lane >> 1) & 3)) << 3);
  int rbb = wave * 32 + (lane & 15);

  __syncthreads();   // us ready

  for (int kt = 0; kt < S_; kt += 64) {
    gld16(gv + kt,                laB);
    gld16(gv + kt + 64 * S_,      laB + 2048);
    gld16(gv + kt + 32,           laB + 4096);
    gld16(gv + kt + 32 + 64 * S_, laB + 6144);
    int ai[16];
    *reinterpret_cast<int4*>(ai)      = *reinterpret_cast<const int4*>(arowp + kt);
    *reinterpret_cast<int4*>(ai + 4)  = *reinterpret_cast<const int4*>(arowp + kt + 4);
    *reinterpret_cast<int4*>(ai + 8)  = *reinterpret_cast<const int4*>(arowp + kt + 8);
    *reinterpret_cast<int4*>(ai + 12) = *reinterpret_cast<const int4*>(arowp + kt + 12);
    ushort uu[16];
    *reinterpret_cast<uint4*>(uu)     = *reinterpret_cast<const uint4*>(&us[kt + cseg]);
    *reinterpret_cast<uint4*>(uu + 8) = *reinterpret_cast<const uint4*>(&us[kt + cseg + 8]);
    ushort av[16];
#pragma unroll
    for (int q = 0; q < 16; ++q) {
      bool nz = (ai[q] != 0);
      av[q] = nz ? uu[q] : (ushort)0;
      dacc += nz ? bf2f(uu[q]) : 0.f;
    }
    *reinterpret_cast<uint4*>(aw0) = reinterpret_cast<uint4*>(av)[0];
    *reinterpret_cast<uint4*>(aw1) = reinterpret_cast<uint4*>(av)[1];
    asm volatile("s_waitcnt vmcnt(0)" ::: "memory");
    __syncthreads();
    bf16x8 a[4][2], bfr[2][2];
#pragma unroll
    for (int mi = 0; mi < 4; ++mi)
#pragma unroll
      for (int ks = 0; ks < 2; ++ks)
        a[mi][ks] = *reinterpret_cast<const bf16x8*>(&As[ks * 2048 + (rowa + mi * 16) * 32 + ksw]);
#pragma unroll
    for (int ni = 0; ni < 2; ++ni)
#pragma unroll
      for (int ks = 0; ks < 2; ++ks)
        bfr[ni][ks] = *reinterpret_cast<const bf16x8*>(&Bs[ks * 4096 + (rbb + ni * 16) * 32 + ksw]);
#pragma unroll
    for (int mi = 0; mi < 4; ++mi)
#pragma unroll
      for (int ni = 0; ni < 2; ++ni)
#pragma unroll
        for (int ks = 0; ks < 2; ++ks)
          acc[mi][ni] = __builtin_amdgcn_mfma_f32_16x16x32_bf16(a[mi][ks], bfr[ni][ks], acc[mi][ni], 0, 0, 0);
    __syncthreads();
  }

  Dred[arow * 4 + (t & 3)] = dacc;
  __syncthreads();
  if (t < 64)
    Dsum[t] = Dred[t * 4] + Dred[t * 4 + 1] + Dred[t * 4 + 2] + Dred[t * 4 + 3];
  __syncthreads();

  int colb = wave * 32 + (lane & 15);
  int rl = (lane >> 4) * 4;
#pragma unroll
  for (int mi = 0; mi < 4; ++mi)
#pragma unroll
    for (int ni = 0; ni < 2; ++ni) {
      int cc = colb + ni * 16;
#pragma unroll
      for (int j = 0; j < 4; ++j) {
        int rr = mi * 16 + rl + j;
        float Di = fmaxf(Dsum[rr], 1e-30f);
        out[((size_t)(b * S_ + i0 + rr)) * DOUT + h * 128 + cc] = acc[mi][ni][j] / Di;
      }
    }
}

// ---------------- launch ----------------
extern "C" void kernel_launch(void* const* d_in, const int* in_sizes, int n_in,
                              void* d_out, int out_size, void* d_ws, size_t ws_size,
                              hipStream_t stream) {
  const float* x    = (const float*)d_in[0];
  const float* mask = (const float*)d_in[1];
  const int*   adj  = (const int*)d_in[2];
  const float* W    = (const float*)d_in[3];
  const float* attw = (const float*)d_in[4];
  float* out = (float*)d_out;

  char* ws = (char*)d_ws;
  ushort* WT  = (ushort*)ws;                               // 2 MiB (1024x1024 bf16, transposed)
  ushort* xhT = (ushort*)(ws + 2097152);                   // 8 MiB (B,H,128,512 bf16)
  ushort* ubf = (ushort*)(ws + 10485760);                  // 64 KiB

  k_prep<<<dim3(256), dim3(256), 0, stream>>>(W, WT);
  k_proj<<<dim3(64, 8), dim3(256), 0, stream>>>(x, WT, attw, mask, xhT, ubf);
  k_attn<<<dim3(8, 8, 8), dim3(256), 0, stream>>>(adj, xhT, ubf, out);
}